// Round 5
// baseline (485.672 us; speedup 1.0000x reference)
//
#include <hip/hip_runtime.h>

// GRU cell, B=16384, E=H=1024. fp32 in/out, bf16 MFMA compute.
//
// R8 structure (vs R6/R7: faithful m201 C-quadrant 8-phase-per-2-tiles port):
//   pre:  cast x,h -> bf16;  6 weights -> transposed bf16, Z/R stacked to N=2048
//   ZR:   [x|h](16384x2048) @ Bzr^T(2048x2048) -> ztb=bf16(sigmoid), ab=bf16(h*sigmoid)
//   H:    [x|ab](16384x2048) @ Wh^T(1024x2048) -> out = h + z*(tanh-h), fp32
// GEMM: 256x256 tile, BK=64, 512 thr / 8 waves (2Mx4N), per-wave 128x64,
// acc[8][4] f32x4. LDS 128 KiB: A,B each [parity][M-half][128 rows][64 cols].
// Even K-tiles always slot 0, odd slot 1 (no dbuf flip).
// Iteration = 2 K-tiles = 8 phases; phase = one C-quadrant (mh,nh) x full K=64:
//   p0:(0,0) reads A-mh0(8)+B-nh0(4) [lgkm(8)]   p1:(0,1) reads B-nh1(4)
//   p2:(1,0) reads A-mh1(8)                      p3:(1,1) reads 0
//   p4..p7 same on the odd tile. B-frags live 4 phases; A-frags 2.
// Phase body: reads -> stage -> [lgkm8] -> barrier -> lgkm0+schedbar ->
//   setprio(1) 16 MFMA setprio(0) -> [vmcnt(6) at p3/p7 only] -> barrier.
// Staging ledger (iter I computes {2I,2I+1}, stages {2I+2,2I+3}):
//   p0: A(2I+1,h1)  p2: B(2I+2,0)  p3: B(2I+2,1)+A(2I+2,0)  p4: A(2I+2,1)
//   p6: B(2I+3,0)   p7: B(2I+3,1)+A(2I+3,0); vm6 at p3/p7.
//   FIFO: enter p0 with 6 outstanding; 6->8->10->14 -vm6-> 6 (invariant).
//   Slot safety: B[p][h] last read at p1/p5 (stage >=p2/p6); A[p][h] last read
//   at p2/p6 (stage >=p3/p7); p0's A[1][1] stage sits behind prev-p7 barrier.
//   Tail iter (tiles 30,31): p0 stages A(31,1), vmcnt(0) at p3, rest pure.
// Swizzle for [128][64] rows (128B stride): 16B-chunk ^= row&7 (3-bit XOR) ->
// exactly 8 words/bank per ds_read_b128 (floor). Inverse on global source
// (chunk (t&7)^((t>>3)&7)), forward on read (row%8 == l4&7 -> immediates).

typedef short bf16x8 __attribute__((ext_vector_type(8)));
typedef float f32x4 __attribute__((ext_vector_type(4)));

template <int V> struct Ic { static constexpr int value = V; };

static __device__ __forceinline__ unsigned short f2bf(float f) {
    unsigned int u = __float_as_uint(f);
    return (unsigned short)((u + 0x7fffu + ((u >> 16) & 1u)) >> 16);
}
static __device__ __forceinline__ float bf2f(unsigned short s) {
    return __uint_as_float(((unsigned int)s) << 16);
}

// ---- cast x and h to bf16 in one launch ------------------------------------
__global__ void cast2_f32_bf16(const float* __restrict__ a,
                               const float* __restrict__ b,
                               unsigned short* __restrict__ da,
                               unsigned short* __restrict__ db, int n) {
    int i = (blockIdx.x * blockDim.x + threadIdx.x) * 4;
    const float* s;
    unsigned short* d;
    int off;
    if (i < n) { s = a; d = da; off = i; }
    else       { s = b; d = db; off = i - n; }
    float4 v = *(const float4*)(s + off);
    ushort4 o;
    o.x = f2bf(v.x); o.y = f2bf(v.y); o.z = f2bf(v.z); o.w = f2bf(v.w);
    *(ushort4*)(d + off) = o;
}

// ---- transpose+cast all 6 weights in one launch ----------------------------
struct TPlan {
    const float* src[6];
    unsigned short* dst[6];  // pre-offset; row stride 2048
};
__global__ void transpose_cast6(TPlan p) {
    __shared__ float t[32][33];
    const float* src = p.src[blockIdx.z];
    unsigned short* dst = p.dst[blockIdx.z];
    int bx = blockIdx.x, by = blockIdx.y;
    int tx = threadIdx.x, ty = threadIdx.y;  // 32 x 8
#pragma unroll
    for (int i = 0; i < 4; ++i)
        t[ty + 8 * i][tx] = src[(by * 32 + ty + 8 * i) * 1024 + bx * 32 + tx];
    __syncthreads();
#pragma unroll
    for (int i = 0; i < 4; ++i) {
        int n = bx * 32 + ty + 8 * i;  // dst row (N)
        int k = by * 32 + tx;          // dst col (K)
        dst[n * 2048 + k] = f2bf(t[tx][ty + 8 * i]);
    }
}

// ---- fused GEMM, 256x256, C-quadrant 8-phase schedule -----------------------
// MODE 0 (ZR): N=2048 (cols 0-1023 = z gate, 1024-2047 = r gate)
// MODE 1 (H):  N=1024
template <int MODE, int NBN_LOG>
__global__ __launch_bounds__(512, 2) void gemm_gru(
        const unsigned short* __restrict__ Alo,  // k in [0,1024), stride 1024
        const unsigned short* __restrict__ Ahi,  // k in [1024,2048), stride 1024
        const unsigned short* __restrict__ Bt,   // [N][2048]
        const float* __restrict__ bias_z,
        const float* __restrict__ bias_r,
        const unsigned short* __restrict__ hb,   // bf16 h
        const unsigned short* __restrict__ ztb_in,
        const float* __restrict__ hf,            // fp32 h
        unsigned short* __restrict__ ztb_out,
        unsigned short* __restrict__ ab_out,
        float* __restrict__ out) {
    constexpr int NBN = 1 << NBN_LOG;
    constexpr int NT = 32;  // 2048 / 64
    // [tile parity][M-half][128 rows][64 cols] bf16 = 16 KB per half-slot
    __shared__ __attribute__((aligned(16))) short As[2][2][128 * 64];
    __shared__ __attribute__((aligned(16))) short Bs[2][2][128 * 64];

    const int t = threadIdx.x;
    const int lane = t & 63;
    const int wave = t >> 6;
    const int wm = wave >> 2, wn = wave & 3;  // 2M x 4N

    // XCD swizzle: all NBN bn-blocks of one bm A-panel are stride-8 in
    // blockIdx -> same XCD L2. nwg % 8 == 0 -> bijective.
    const int i = blockIdx.x;
    const int bml = i & 7;
    const int bn = (i >> 3) & (NBN - 1);
    const int bmg = i >> (3 + NBN_LOG);
    const int bm = bmg * 8 + bml;

    const int l4 = lane & 15, kg = lane >> 4;
    // swizzled k-chunk offsets (shorts) for kk=0,1: chunk (kk*4+kg)^(l4&7)
    const int cs0 = ((kg) ^ (l4 & 7)) * 8;
    const int cs1 = ((4 + kg) ^ (l4 & 7)) * 8;
    // per-parity fragment base pointers (row term l4*64; frag rows add
    // compile-time multiples of 16*64)
    const short* aB[2] = { &As[0][wm][l4 * 64], &As[1][wm][l4 * 64] };
    const short* bB[2] = { &Bs[0][wn >> 1][((wn & 1) * 64 + l4) * 64],
                           &Bs[1][wn >> 1][((wn & 1) * 64 + l4) * 64] };

    // staging: thread t, inst j -> LDS row j*64 + (t>>3), chunk t&7 (linear);
    // inverse swizzle on global source: chunk (t&7) ^ ((t>>3)&7).
    const int srow = t >> 3;                            // 0..63
    const int schunk = (((t & 7) ^ ((t >> 3) & 7)) * 8);  // shorts
    const int rowA0 = bm * 256;
    const int rowB0 = bn * 256;

    f32x4 acc[8][4] = {};
    bf16x8 a[2][4];    // [kk][m]  A frags of current quadrant row-half
    bf16x8 bq[2][2][2];  // [nh][kk][n]  B frags, live 4 phases

    // one half-slot = 128 rows x 64 cols = 16 KB = 2 loads/thread
    auto stage_half = [&](const unsigned short* src, int stride, int grow0,
                          int kcol, short* dst) {
#pragma unroll
        for (int j = 0; j < 2; ++j) {
            const unsigned short* g =
                src + (size_t)(grow0 + j * 64 + srow) * stride + (kcol + schunk);
            __builtin_amdgcn_global_load_lds(
                (const __attribute__((address_space(1))) void*)g,
                (__attribute__((address_space(3))) void*)(dst + (j * 512 + wave * 64) * 8),
                16, 0, 0);
        }
    };
    auto stA = [&](int T, int h, short* dst) {
        const unsigned short* Ab = (T < 16) ? Alo : Ahi;
        stage_half(Ab, 1024, rowA0 + h * 128, (T * 64) & 1023, dst);
    };
    auto stB = [&](int T, int h, short* dst) {
        stage_half(Bt, 2048, rowB0 + h * 128, T * 64, dst);
    };

    auto nop = [] {};
    auto vm6 = [] { asm volatile("s_waitcnt vmcnt(6)" ::: "memory"); };
    auto vm0 = [] { asm volatile("s_waitcnt vmcnt(0)" ::: "memory"); };

    // Phase <TP parity, MH, NH, RA, RB>: reads -> stage -> [lgkm8] -> barrier
    // -> lgkm0 -> MFMA quadrant (MH,NH) full K=64 -> vm -> barrier.
    auto phase = [&](auto TPc, auto MHc, auto NHc, auto RAc, auto RBc,
                     auto stage, auto vmw) {
        constexpr int TP = decltype(TPc)::value;
        constexpr int MH = decltype(MHc)::value;
        constexpr int NH = decltype(NHc)::value;
        constexpr int RA = decltype(RAc)::value;
        constexpr int RB = decltype(RBc)::value;
        if constexpr (RA) {
#pragma unroll
            for (int m = 0; m < 4; ++m) {
                a[0][m] = *(const bf16x8*)(aB[TP] + (MH * 64 + m * 16) * 64 + cs0);
                a[1][m] = *(const bf16x8*)(aB[TP] + (MH * 64 + m * 16) * 64 + cs1);
            }
        }
        if constexpr (RB) {
#pragma unroll
            for (int n = 0; n < 2; ++n) {
                bq[NH][0][n] = *(const bf16x8*)(bB[TP] + (NH * 32 + n * 16) * 64 + cs0);
                bq[NH][1][n] = *(const bf16x8*)(bB[TP] + (NH * 32 + n * 16) * 64 + cs1);
            }
        }
        stage();
        if constexpr (RA && RB)
            asm volatile("s_waitcnt lgkmcnt(8)" ::: "memory");
        __builtin_amdgcn_s_barrier();
        asm volatile("s_waitcnt lgkmcnt(0)" ::: "memory");
        __builtin_amdgcn_sched_barrier(0);
        __builtin_amdgcn_s_setprio(1);
#pragma unroll
        for (int kk = 0; kk < 2; ++kk)
#pragma unroll
            for (int m = 0; m < 4; ++m)
#pragma unroll
                for (int n = 0; n < 2; ++n)
                    acc[MH * 4 + m][NH * 2 + n] =
                        __builtin_amdgcn_mfma_f32_16x16x32_bf16(
                            a[kk][m], bq[NH][kk][n],
                            acc[MH * 4 + m][NH * 2 + n], 0, 0, 0);
        __builtin_amdgcn_s_setprio(0);
        vmw();
        __builtin_amdgcn_s_barrier();
    };

    // Prologue: tile0 full + tile1 {A0,B0,B1} = 14 loads; vm6 -> tile0 landed,
    // 6 in flight (matches steady-state p0 entry).
    stA(0, 0, &As[0][0][0]); stA(0, 1, &As[0][1][0]);
    stB(0, 0, &Bs[0][0][0]); stB(0, 1, &Bs[0][1][0]);
    stA(1, 0, &As[1][0][0]);
    stB(1, 0, &Bs[1][0][0]); stB(1, 1, &Bs[1][1][0]);
    asm volatile("s_waitcnt vmcnt(6)" ::: "memory");
    __builtin_amdgcn_s_barrier();

    // 15 generic iterations: tiles {2I, 2I+1}, staging {2I+2, 2I+3}.
    for (int I = 0; I < 15; ++I) {
        const int To = 2 * I + 1, T2 = 2 * I + 2, T3 = 2 * I + 3;
        phase(Ic<0>{}, Ic<0>{}, Ic<0>{}, Ic<1>{}, Ic<1>{},
              [&] { stA(To, 1, &As[1][1][0]); }, nop);
        phase(Ic<0>{}, Ic<0>{}, Ic<1>{}, Ic<0>{}, Ic<1>{}, nop, nop);
        phase(Ic<0>{}, Ic<1>{}, Ic<0>{}, Ic<1>{}, Ic<0>{},
              [&] { stB(T2, 0, &Bs[0][0][0]); }, nop);
        phase(Ic<0>{}, Ic<1>{}, Ic<1>{}, Ic<0>{}, Ic<0>{},
              [&] { stB(T2, 1, &Bs[0][1][0]); stA(T2, 0, &As[0][0][0]); }, vm6);
        phase(Ic<1>{}, Ic<0>{}, Ic<0>{}, Ic<1>{}, Ic<1>{},
              [&] { stA(T2, 1, &As[0][1][0]); }, nop);
        phase(Ic<1>{}, Ic<0>{}, Ic<1>{}, Ic<0>{}, Ic<1>{}, nop, nop);
        phase(Ic<1>{}, Ic<1>{}, Ic<0>{}, Ic<1>{}, Ic<0>{},
              [&] { stB(T3, 0, &Bs[1][0][0]); }, nop);
        phase(Ic<1>{}, Ic<1>{}, Ic<1>{}, Ic<0>{}, Ic<0>{},
              [&] { stB(T3, 1, &Bs[1][1][0]); stA(T3, 0, &As[1][0][0]); }, vm6);
    }
    // Tail iteration: tiles {30, 31}; only A(31,1) left to stage.
    phase(Ic<0>{}, Ic<0>{}, Ic<0>{}, Ic<1>{}, Ic<1>{},
          [&] { stA(31, 1, &As[1][1][0]); }, nop);
    phase(Ic<0>{}, Ic<0>{}, Ic<1>{}, Ic<0>{}, Ic<1>{}, nop, nop);
    phase(Ic<0>{}, Ic<1>{}, Ic<0>{}, Ic<1>{}, Ic<0>{}, nop, nop);
    phase(Ic<0>{}, Ic<1>{}, Ic<1>{}, Ic<0>{}, Ic<0>{}, nop, vm0);
    phase(Ic<1>{}, Ic<0>{}, Ic<0>{}, Ic<1>{}, Ic<1>{}, nop, nop);
    phase(Ic<1>{}, Ic<0>{}, Ic<1>{}, Ic<0>{}, Ic<1>{}, nop, nop);
    phase(Ic<1>{}, Ic<1>{}, Ic<0>{}, Ic<1>{}, Ic<0>{}, nop, nop);
    phase(Ic<1>{}, Ic<1>{}, Ic<1>{}, Ic<0>{}, Ic<0>{}, nop, nop);

    // Epilogue. C/D layout: col = lane&15, row = (lane>>4)*4 + reg  [m89]
    const int q4 = kg * 4;
#pragma unroll
    for (int mi = 0; mi < 8; ++mi) {
        int row0 = bm * 256 + wm * 128 + mi * 16 + q4;
#pragma unroll
        for (int ni = 0; ni < 4; ++ni) {
            int colg = bn * 256 + wn * 64 + ni * 16 + l4;
            if (MODE == 0) {
                bool isZ = colg < 1024;  // block-uniform (256 | 1024)
                int col = colg & 1023;
                float bz = isZ ? bias_z[col] : bias_r[col];
#pragma unroll
                for (int r = 0; r < 4; ++r) {
                    int idx = (row0 + r) * 1024 + col;
                    float v = acc[mi][ni][r] + bz;
                    float s = 1.0f / (1.0f + __expf(-v));
                    if (isZ) ztb_out[idx] = f2bf(s);
                    else     ab_out[idx] = f2bf(bf2f(hb[idx]) * s);
                }
            } else {
                float bz = bias_z[colg];
#pragma unroll
                for (int r = 0; r < 4; ++r) {
                    int idx = (row0 + r) * 1024 + colg;
                    float v = acc[mi][ni][r] + bz;
                    // tanh, saturation-safe: 1 - 2/(e^{2v}+1)
                    float e = __expf(2.0f * v);
                    float ht = 1.0f - 2.0f / (e + 1.0f);
                    float hv = hf[idx];
                    float z = bf2f(ztb_in[idx]);
                    out[idx] = fmaf(z, ht - hv, hv);
                }
            }
        }
    }
}

extern "C" void kernel_launch(void* const* d_in, const int* in_sizes, int n_in,
                              void* d_out, int out_size, void* d_ws, size_t ws_size,
                              hipStream_t stream) {
    const float* x    = (const float*)d_in[0];
    const float* h    = (const float*)d_in[1];
    const float* W_ri = (const float*)d_in[2];
    const float* b_ri = (const float*)d_in[3];
    const float* W_rh = (const float*)d_in[4];
    const float* W_zi = (const float*)d_in[5];
    const float* b_zi = (const float*)d_in[6];
    const float* W_zh = (const float*)d_in[7];
    const float* W_hi = (const float*)d_in[8];
    const float* b_hi = (const float*)d_in[9];
    const float* W_hh = (const float*)d_in[10];
    float* out = (float*)d_out;

    const size_t MB = 1024ull * 1024ull;
    char* ws = (char*)d_ws;
    unsigned short* xb   = (unsigned short*)(ws);             // 32 MB
    unsigned short* hb   = (unsigned short*)(ws + 32 * MB);   // 32 MB
    unsigned short* ab   = (unsigned short*)(ws + 64 * MB);   // 32 MB
    unsigned short* ztb  = (unsigned short*)(ws + 96 * MB);   // 32 MB
    unsigned short* Bzr  = (unsigned short*)(ws + 128 * MB);  // 8 MB  [2048][2048]
    unsigned short* Bh   = (unsigned short*)(ws + 136 * MB);  // 4 MB  [1024][2048]

    const int NELEM = 16384 * 1024;
    cast2_f32_bf16<<<2 * NELEM / (256 * 4), 256, 0, stream>>>(x, h, xb, hb, NELEM);

    TPlan p;
    p.src[0] = W_zi; p.dst[0] = Bzr + 0 * 2048 + 0;
    p.src[1] = W_zh; p.dst[1] = Bzr + 0 * 2048 + 1024;
    p.src[2] = W_ri; p.dst[2] = Bzr + 1024 * 2048 + 0;
    p.src[3] = W_rh; p.dst[3] = Bzr + 1024 * 2048 + 1024;
    p.src[4] = W_hi; p.dst[4] = Bh + 0;
    p.src[5] = W_hh; p.dst[5] = Bh + 1024;
    transpose_cast6<<<dim3(32, 32, 6), dim3(32, 8), 0, stream>>>(p);

    // ZR: 64 bm * 8 bn = 512 blocks; H: 64 bm * 4 bn = 256 blocks
    gemm_gru<0, 3><<<512, 512, 0, stream>>>(xb, hb, Bzr, b_zi, b_ri,
                                            hb, nullptr, nullptr,
                                            ztb, ab, nullptr);
    gemm_gru<1, 2><<<256, 512, 0, stream>>>(xb, ab, Bh, b_hi, nullptr,
                                            nullptr, ztb, h,
                                            nullptr, nullptr, out);
}